// Round 1
// baseline (71.431 us; speedup 1.0000x reference)
//
#include <hip/hip_runtime.h>

// Fuzzy decoder: num[p,s,o] = max_k min(t0[s,k], t_p[k,o]); out = t + num - t*num.
// R1: split-K (2 halves) x 512 blocks keeps 8 waves/CU while widening the
// per-thread tile to 2s x 4o (one ds_read_b128 for B per k2).
// LDS read instrs per (out*k): 0.5 -> 0.25; bytes: 2.0 -> 1.5.
// f16 k-half partials land byte-interleaved in OUT (race-free 2B stores,
// no workspace -- R4 lesson); combine kernel does max(halves) + amalgamate.
// Numerics bit-identical to the 69.5us kernel (same pkrtz/f16 min-max path).

#define SDIM 512
#define TS 32        // s-tile per block
#define TO 64        // o-tile per block
#define KHALF 256    // k per block (split-K factor 2)
#define BK 64        // k per chunk
#define BK2 32       // packed k-pairs per chunk
#define NCH (KHALF / BK)   // 4 chunks
#define ASTR 34      // 32 + 2 pad (h2 units): A reads broadcast, stores 2-way max
#define BSTR 68      // 64 + 4 pad (h2 units): 272B row stride -> b128 conflict-free

typedef _Float16 h2 __attribute__((ext_vector_type(2)));

__device__ __forceinline__ h2 pack2(float a, float b) {
    return __builtin_bit_cast(h2, __builtin_amdgcn_cvt_pkrtz(a, b));  // v_cvt_pkrtz_f16_f32
}
__device__ __forceinline__ h2 pmin(h2 a, h2 b) { return __builtin_elementwise_min(a, b); }
__device__ __forceinline__ h2 pmax(h2 a, h2 b) { return __builtin_elementwise_max(a, b); }
__device__ __forceinline__ h2 bch2(unsigned u) { return __builtin_bit_cast(h2, u); }
__device__ __forceinline__ unsigned bcu(h2 v) { return __builtin_bit_cast(unsigned, v); }

__global__ __launch_bounds__(256, 2) void compose_partial(
        const float* __restrict__ t, float* __restrict__ out) {
    __shared__ h2 Als[BK2][ASTR];   // A^T: [k2][s], padded
    __shared__ h2 Bls[BK2][BSTR];   // B:   [k2][o], padded

    const int tid = threadIdx.x;
    const int o0 = blockIdx.x * TO;   // 8 o-tiles
    const int s0 = blockIdx.y * TS;   // 16 s-tiles
    const int p  = blockIdx.z >> 1;   // predicate
    const int kh = blockIdx.z & 1;    // k-half
    const int kb = kh * KHALF;

    const float* __restrict__ B = t + p * (SDIM * SDIM);

    // compute mapping: 2 s-rows x 4 o-cols per thread
    const int ol = (tid & 15) * 4;
    const int sl = (tid >> 4) * 2;
    // A staging: s-row ar (0..31), k-float4 pair aq (0..7)
    const int ar = tid >> 3, aq = tid & 7;
    // B staging: k-pair bk2 (0..31), 8-float o-group bq (0..7)
    const int bk2 = tid >> 3, bq = tid & 7;

    const float4* __restrict__ Arow =
        reinterpret_cast<const float4*>(t + (s0 + ar) * SDIM);

    h2 acc[2][4];
    #pragma unroll
    for (int j = 0; j < 2; ++j)
        #pragma unroll
        for (int i = 0; i < 4; ++i) acc[j][i] = pack2(0.f, 0.f);

    float4 fa0, fa1, fx, fx2, fy, fy2;
    // prologue: load chunk 0
    {
        const int kf = kb / 4 + aq * 2;
        fa0 = Arow[kf];
        fa1 = Arow[kf + 1];
        const float* __restrict__ Bb = B + (kb + 2 * bk2) * SDIM + o0 + bq * 8;
        fx  = *reinterpret_cast<const float4*>(Bb);
        fx2 = *reinterpret_cast<const float4*>(Bb + 4);
        fy  = *reinterpret_cast<const float4*>(Bb + SDIM);
        fy2 = *reinterpret_cast<const float4*>(Bb + SDIM + 4);
    }

    for (int c = 0; c < NCH; ++c) {
        // staged regs -> LDS
        {
            const int k2b = aq * 4;
            Als[k2b + 0][ar] = pack2(fa0.x, fa0.y);
            Als[k2b + 1][ar] = pack2(fa0.z, fa0.w);
            Als[k2b + 2][ar] = pack2(fa1.x, fa1.y);
            Als[k2b + 3][ar] = pack2(fa1.z, fa1.w);
            uint4 u0, u1;   // h2[o] = (row 2*bk2, row 2*bk2+1)
            u0.x = bcu(pack2(fx.x, fy.x));
            u0.y = bcu(pack2(fx.y, fy.y));
            u0.z = bcu(pack2(fx.z, fy.z));
            u0.w = bcu(pack2(fx.w, fy.w));
            u1.x = bcu(pack2(fx2.x, fy2.x));
            u1.y = bcu(pack2(fx2.y, fy2.y));
            u1.z = bcu(pack2(fx2.z, fy2.z));
            u1.w = bcu(pack2(fx2.w, fy2.w));
            *reinterpret_cast<uint4*>(&Bls[bk2][bq * 8]) = u0;
            *reinterpret_cast<uint4*>(&Bls[bk2][bq * 8 + 4]) = u1;
        }
        __syncthreads();

        // prefetch next chunk (overlaps compute)
        if (c + 1 < NCH) {
            const int k0 = kb + (c + 1) * BK;
            const int kf = k0 / 4 + aq * 2;
            fa0 = Arow[kf];
            fa1 = Arow[kf + 1];
            const float* __restrict__ Bb = B + (k0 + 2 * bk2) * SDIM + o0 + bq * 8;
            fx  = *reinterpret_cast<const float4*>(Bb);
            fx2 = *reinterpret_cast<const float4*>(Bb + 4);
            fy  = *reinterpret_cast<const float4*>(Bb + SDIM);
            fy2 = *reinterpret_cast<const float4*>(Bb + SDIM + 4);
        }

        // inner loop: per k2 = 1 b64 (A) + 1 b128 (B) + 16 pk instrs
        #pragma unroll
        for (int k2 = 0; k2 < BK2; ++k2) {
            const uint2 ua = *reinterpret_cast<const uint2*>(&Als[k2][sl]);
            const uint4 ub = *reinterpret_cast<const uint4*>(&Bls[k2][ol]);
            const h2 a0 = bch2(ua.x), a1 = bch2(ua.y);
            const h2 b0 = bch2(ub.x), b1 = bch2(ub.y);
            const h2 b2 = bch2(ub.z), b3 = bch2(ub.w);
            acc[0][0] = pmax(acc[0][0], pmin(a0, b0));
            acc[0][1] = pmax(acc[0][1], pmin(a0, b1));
            acc[0][2] = pmax(acc[0][2], pmin(a0, b2));
            acc[0][3] = pmax(acc[0][3], pmin(a0, b3));
            acc[1][0] = pmax(acc[1][0], pmin(a1, b0));
            acc[1][1] = pmax(acc[1][1], pmin(a1, b1));
            acc[1][2] = pmax(acc[1][2], pmin(a1, b2));
            acc[1][3] = pmax(acc[1][3], pmin(a1, b3));
        }
        __syncthreads();
    }

    // f16 k-half partial -> OUT, byte-interleaved: word(elem) = (kh0, kh1)
    unsigned short* __restrict__ op = reinterpret_cast<unsigned short*>(out);
    #pragma unroll
    for (int j = 0; j < 2; ++j) {
        const int row = s0 + sl + j;
        #pragma unroll
        for (int i = 0; i < 4; ++i) {
            const int o = o0 + ol + i;
            const float nm = fmaxf((float)acc[j][i][0], (float)acc[j][i][1]);
            const _Float16 hh = (_Float16)nm;
            op[(((p * SDIM) + row) * SDIM + o) * 2 + kh] =
                __builtin_bit_cast(unsigned short, hh);
        }
    }
}

// combine: num = max(f16 halves) packed in out's own word; out = t + num - t*num.
// Each thread rewrites exactly the uint4 it read -> race-free in-place.
__global__ __launch_bounds__(256) void combine_amalg(
        const float* __restrict__ t, float* __restrict__ out) {
    const int idx = blockIdx.x * 256 + threadIdx.x;   // 131072 uint4 = 2 MB exact
    const uint4 w = reinterpret_cast<const uint4*>(out)[idx];
    const float4 tv = reinterpret_cast<const float4*>(t)[idx];
    const unsigned wv[4] = {w.x, w.y, w.z, w.w};
    const float tf[4] = {tv.x, tv.y, tv.z, tv.w};
    float rs[4];
    #pragma unroll
    for (int i = 0; i < 4; ++i) {
        const _Float16 h0 = __builtin_bit_cast(_Float16, (unsigned short)(wv[i] & 0xffffu));
        const _Float16 h1 = __builtin_bit_cast(_Float16, (unsigned short)(wv[i] >> 16));
        const float num = fmaxf((float)h0, (float)h1);
        rs[i] = tf[i] + num - tf[i] * num;
    }
    float4 r;
    r.x = rs[0]; r.y = rs[1]; r.z = rs[2]; r.w = rs[3];
    reinterpret_cast<float4*>(out)[idx] = r;
}

extern "C" void kernel_launch(void* const* d_in, const int* in_sizes, int n_in,
                              void* d_out, int out_size, void* d_ws, size_t ws_size,
                              hipStream_t stream) {
    const float* t = (const float*)d_in[0];
    float* out = (float*)d_out;
    dim3 g1(SDIM / TO, SDIM / TS, 4);   // 8 x 16 x (2p * 2kh) = 512 blocks
    compose_partial<<<g1, 256, 0, stream>>>(t, out);
    combine_amalg<<<dim3(512), 256, 0, stream>>>(t, out);
}

// Round 2
// 69.922 us; speedup vs baseline: 1.0216x; 1.0216x over previous
//
#include <hip/hip_runtime.h>

// Fuzzy decoder: num[p,s,o] = max_k min(t0[s,k], t_p[k,o]); out = t + num - t*num.
// R2: kill the chunk/barrier structure. R1 showed halving LDS instrs was neutral
// -> compose is stall-bound (8 barriers/block draining vmcnt+lgkmcnt at 2 waves/SIMD),
// not LDS-throughput bound. Whole K-half tile (48KB) staged once, ONE barrier,
// then an uninterrupted 128-iter ds_read -> v_pk_min/max loop the compiler can
// pipeline with counted lgkmcnt. Partials: plane-in-16B f16 layout in OUT
// (no workspace -- R4 lesson), coalesced uint2 stores; combine reads exactly
// the uint4 it overwrites (race-free in-place). Numerics bit-identical to r0/r1.

#define SDIM 512
#define TS 32        // s-tile per block
#define TO 64        // o-tile per block
#define KHALF 256    // k per block (split-K factor 2)
#define K2H 128      // packed k-pairs per block
#define ASTR 34      // A^T stride (h2): 32 + 2 pad, even -> b64-aligned reads
#define BSTR 68      // B stride (h2): 64 + 4 pad, mult of 4 -> b128-aligned

typedef _Float16 h2 __attribute__((ext_vector_type(2)));

__device__ __forceinline__ h2 pack2(float a, float b) {
    return __builtin_bit_cast(h2, __builtin_amdgcn_cvt_pkrtz(a, b));  // v_cvt_pkrtz_f16_f32
}
__device__ __forceinline__ h2 pmin(h2 a, h2 b) { return __builtin_elementwise_min(a, b); }
__device__ __forceinline__ h2 pmax(h2 a, h2 b) { return __builtin_elementwise_max(a, b); }
__device__ __forceinline__ h2 bch2(unsigned u) { return __builtin_bit_cast(h2, u); }
__device__ __forceinline__ unsigned bcu(h2 v) { return __builtin_bit_cast(unsigned, v); }

__global__ __launch_bounds__(256, 2) void compose_partial(
        const float* __restrict__ t, float* __restrict__ out) {
    __shared__ h2 Als[K2H][ASTR];   // A^T: [k2][s]  (17408 B)
    __shared__ h2 Bls[K2H][BSTR];   // B:   [k2][o]  (34816 B)  total 51 KB

    const int tid = threadIdx.x;
    const int o0 = blockIdx.x * TO;   // 8 o-tiles
    const int s0 = blockIdx.y * TS;   // 16 s-tiles
    const int p  = blockIdx.z >> 1;   // predicate
    const int kh = blockIdx.z & 1;    // k-half
    const int kb = kh * KHALF;

    const float* __restrict__ Bp = t + p * (SDIM * SDIM);

    // ---- stage A: rows s0..s0+31, k in [kb,kb+256) -> Als[k2][s]
    const int ar = tid >> 3, aq = tid & 7;     // 32 rows x 8 f4-slots
    const float4* __restrict__ Arow =
        reinterpret_cast<const float4*>(t + (s0 + ar) * SDIM + kb);
    float4 fa[8];
    #pragma unroll
    for (int j = 0; j < 8; ++j) fa[j] = Arow[aq + 8 * j];   // coalesced 128B/8 lanes

    // ---- stage B: rows kb..kb+255, cols o0..o0+63 -> Bls[k2][o]
    const int bq = tid & 15, bp = tid >> 4;    // 16 f4-cols x 16 row-pair groups
    const float* __restrict__ Bb = Bp + kb * SDIM + o0 + bq * 4;
    float4 fx[8], fy[8];
    #pragma unroll
    for (int j = 0; j < 8; ++j) {
        const int r2 = (bp + 16 * j) * 2;      // row pair
        fx[j] = *reinterpret_cast<const float4*>(Bb + r2 * SDIM);
        fy[j] = *reinterpret_cast<const float4*>(Bb + (r2 + 1) * SDIM);
    }

    #pragma unroll
    for (int j = 0; j < 8; ++j) {              // A pack: b32 stores, <=2-way banks
        const int k2b = 2 * (aq + 8 * j);
        Als[k2b    ][ar] = pack2(fa[j].x, fa[j].y);
        Als[k2b + 1][ar] = pack2(fa[j].z, fa[j].w);
    }
    #pragma unroll
    for (int j = 0; j < 8; ++j) {              // B pack: one b128 store per pair
        uint4 u;                                // h2[o] = (row even, row odd)
        u.x = bcu(pack2(fx[j].x, fy[j].x));
        u.y = bcu(pack2(fx[j].y, fy[j].y));
        u.z = bcu(pack2(fx[j].z, fy[j].z));
        u.w = bcu(pack2(fx[j].w, fy[j].w));
        *reinterpret_cast<uint4*>(&Bls[bp + 16 * j][bq * 4]) = u;
    }
    __syncthreads();   // the ONLY barrier

    // ---- compute: 2s x 4o per thread, K=256 straight through
    const int ol = (tid & 15) * 4;
    const int sl = (tid >> 4) * 2;

    h2 acc[2][4];
    #pragma unroll
    for (int j = 0; j < 2; ++j)
        #pragma unroll
        for (int i = 0; i < 4; ++i) acc[j][i] = pack2(0.f, 0.f);

    #pragma unroll 8
    for (int k2 = 0; k2 < K2H; ++k2) {
        const uint2 ua = *reinterpret_cast<const uint2*>(&Als[k2][sl]);   // broadcast
        const uint4 ub = *reinterpret_cast<const uint4*>(&Bls[k2][ol]);   // 16-addr b128
        const h2 a0 = bch2(ua.x), a1 = bch2(ua.y);
        const h2 b0 = bch2(ub.x), b1 = bch2(ub.y);
        const h2 b2 = bch2(ub.z), b3 = bch2(ub.w);
        acc[0][0] = pmax(acc[0][0], pmin(a0, b0));
        acc[0][1] = pmax(acc[0][1], pmin(a0, b1));
        acc[0][2] = pmax(acc[0][2], pmin(a0, b2));
        acc[0][3] = pmax(acc[0][3], pmin(a0, b3));
        acc[1][0] = pmax(acc[1][0], pmin(a1, b0));
        acc[1][1] = pmax(acc[1][1], pmin(a1, b1));
        acc[1][2] = pmax(acc[1][2], pmin(a1, b2));
        acc[1][3] = pmax(acc[1][3], pmin(a1, b3));
    }

    // ---- epilogue: f16 partials into OUT, plane-in-16B layout:
    // elem group g (4 elems) owns ushorts [8g..8g+8): [4x kh0 | 4x kh1]
    unsigned short* __restrict__ us = reinterpret_cast<unsigned short*>(out);
    #pragma unroll
    for (int j = 0; j < 2; ++j) {
        const int row = s0 + sl + j;
        const int e = ((p * SDIM) + row) * SDIM + o0 + ol;   // mult of 4
        const float n0 = fmaxf((float)acc[j][0][0], (float)acc[j][0][1]);
        const float n1 = fmaxf((float)acc[j][1][0], (float)acc[j][1][1]);
        const float n2 = fmaxf((float)acc[j][2][0], (float)acc[j][2][1]);
        const float n3 = fmaxf((float)acc[j][3][0], (float)acc[j][3][1]);
        uint2 w;                       // pkrtz exact: values already f16
        w.x = bcu(pack2(n0, n1));
        w.y = bcu(pack2(n2, n3));
        *reinterpret_cast<uint2*>(&us[e * 2 + kh * 4]) = w;   // coalesced 8B store
    }
}

// combine: num = max(f16 kh-halves); out = t + num - t*num.
// Each thread reads exactly the uint4 it overwrites -> race-free in-place.
__global__ __launch_bounds__(256) void combine_amalg(
        const float* __restrict__ t, float* __restrict__ out) {
    const int g = blockIdx.x * 256 + threadIdx.x;   // 131072 groups of 4 elems
    const uint4 w = reinterpret_cast<const uint4*>(out)[g];
    const float4 tv = reinterpret_cast<const float4*>(t)[g];
    const h2 n01 = pmax(bch2(w.x), bch2(w.z));      // kh0 vs kh1, elems 0,1
    const h2 n23 = pmax(bch2(w.y), bch2(w.w));      // elems 2,3
    const float n[4] = {(float)n01[0], (float)n01[1], (float)n23[0], (float)n23[1]};
    const float tf[4] = {tv.x, tv.y, tv.z, tv.w};
    float4 r;
    r.x = tf[0] + n[0] - tf[0] * n[0];
    r.y = tf[1] + n[1] - tf[1] * n[1];
    r.z = tf[2] + n[2] - tf[2] * n[2];
    r.w = tf[3] + n[3] - tf[3] * n[3];
    reinterpret_cast<float4*>(out)[g] = r;
}

extern "C" void kernel_launch(void* const* d_in, const int* in_sizes, int n_in,
                              void* d_out, int out_size, void* d_ws, size_t ws_size,
                              hipStream_t stream) {
    const float* t = (const float*)d_in[0];
    float* out = (float*)d_out;
    dim3 g1(SDIM / TO, SDIM / TS, 4);   // 8 x 16 x (2p * 2kh) = 512 blocks
    compose_partial<<<g1, 256, 0, stream>>>(t, out);
    combine_amalg<<<dim3(512), 256, 0, stream>>>(t, out);
}